// Round 10
// baseline (262.211 us; speedup 1.0000x reference)
//
#include <hip/hip_runtime.h>

typedef __bf16 bf16x8 __attribute__((ext_vector_type(8)));
typedef float f32x4 __attribute__((ext_vector_type(4)));
typedef unsigned short u16x8 __attribute__((ext_vector_type(8)));

__device__ __forceinline__ unsigned short f2bf(float f) {
  return __builtin_bit_cast(unsigned short, (__bf16)f);   // v_cvt_pk_bf16_f32, RNE
}

__device__ __forceinline__ void gload16(const void* g, void* l) {
  __builtin_amdgcn_global_load_lds((const __attribute__((address_space(1))) unsigned int*)g,
                                   (__attribute__((address_space(3))) unsigned int*)l,
                                   16, 0, 0);
}

// DPP row_ror reductions over 16-lane rows (VALU pipe, no LDS traffic)
template <int N>
__device__ __forceinline__ float rormax(float x) {
  int r = __builtin_amdgcn_update_dpp(0, __builtin_bit_cast(int, x), 0x120 + N, 0xF, 0xF, true);
  return fmaxf(x, __builtin_bit_cast(float, r));
}
template <int N>
__device__ __forceinline__ float rorsum(float x) {
  int r = __builtin_amdgcn_update_dpp(0, __builtin_bit_cast(int, x), 0x120 + N, 0xF, 0xF, true);
  return x + __builtin_bit_cast(float, r);
}
__device__ __forceinline__ float red16max(float x) {
  x = rormax<8>(x); x = rormax<4>(x); x = rormax<2>(x); return rormax<1>(x);
}
__device__ __forceinline__ float red16sum(float x) {
  x = rorsum<8>(x); x = rorsum<4>(x); x = rorsum<2>(x); return rorsum<1>(x);
}

// ---------------------------------------------------------------------------
// f32 -> bf16 conversion for {x, qkv_w, proj_w}
// ---------------------------------------------------------------------------
__global__ __launch_bounds__(256)
void cvt3_f32_bf16(const float* __restrict__ s0, unsigned short* __restrict__ d0, int n0,
                   const float* __restrict__ s1, unsigned short* __restrict__ d1, int n1,
                   const float* __restrict__ s2, unsigned short* __restrict__ d2)
{
  int blk = blockIdx.x;
  const float* s; unsigned short* d;
  if (blk < n0)            { s = s0; d = d0; }
  else if (blk < n0 + n1)  { s = s1; d = d1; blk -= n0; }
  else                     { s = s2; d = d2; blk -= n0 + n1; }
  const size_t e = ((size_t)blk * 256 + threadIdx.x) * 8;
  const float4 a = *(const float4*)(s + e);
  const float4 b = *(const float4*)(s + e + 4);
  u16x8 v;
  v[0] = f2bf(a.x); v[1] = f2bf(a.y); v[2] = f2bf(a.z); v[3] = f2bf(a.w);
  v[4] = f2bf(b.x); v[5] = f2bf(b.y); v[6] = f2bf(b.z); v[7] = f2bf(b.w);
  *(u16x8*)(d + e) = v;
}

// ---------------------------------------------------------------------------
// 256x256 8-phase GEMM, ledger v2: each half-tile staged at its EARLIEST
// legal phase (ph0:A1h1, ph2:B0h0, ph3:B0h1+A0h0, ph4:A0h1, ph6:B1h0,
// ph7:B1h1+A1h0); steady-state waits vmcnt(6) at ph3/ph7 (drain-order
// verified: ph3 drains exactly buf1's A+B, ph7 exactly buf0's).
// ---------------------------------------------------------------------------
#define STG(XS, Xg, buf, half, kt)                                              \
  { gload16((Xg) + (size_t)((half)*128 + srow8) * K + (kt)*64 + scol,           \
            (XS) + (buf)*32768 + (half)*16384 + wid*1024);                      \
    gload16((Xg) + (size_t)((half)*128 + 64 + srow8) * K + (kt)*64 + scol,      \
            (XS) + (buf)*32768 + (half)*16384 + 8192 + wid*1024); }

#define LDA(buf, ih)                                                            \
  { _Pragma("unroll") for (int i = 0; i < 4; ++i) {                             \
      const int ro = (buf)*32768 + arow + ((ih)*64 + i*16)*128;                 \
      af[i][0] = *(const bf16x8*)(As + ro + cbs0);                              \
      af[i][1] = *(const bf16x8*)(As + ro + cbs1); } }

#define LDB(buf, jh, BF)                                                        \
  { _Pragma("unroll") for (int j = 0; j < 2; ++j) {                             \
      const int ro = (buf)*32768 + brow + (((jh)*2 + j)*16)*128;                \
      BF[j][0] = *(const bf16x8*)(Bs + ro + cbs0);                              \
      BF[j][1] = *(const bf16x8*)(Bs + ro + cbs1); } }

#define MM(ih, jh, BF)                                                          \
  { _Pragma("unroll") for (int i = 0; i < 4; ++i)                               \
    _Pragma("unroll") for (int j = 0; j < 2; ++j)                               \
    _Pragma("unroll") for (int kk = 0; kk < 2; ++kk)                            \
      acc[(ih)*4+i][(jh)*2+j] = __builtin_amdgcn_mfma_f32_16x16x32_bf16(        \
          af[i][kk], BF[j][kk], acc[(ih)*4+i][(jh)*2+j], 0, 0, 0); }

#define BAR1_12() { asm volatile("s_waitcnt lgkmcnt(8)" ::: "memory");          \
                    __builtin_amdgcn_s_barrier();                               \
                    asm volatile("s_waitcnt lgkmcnt(0)" ::: "memory");          \
                    __builtin_amdgcn_sched_barrier(0);                          \
                    __builtin_amdgcn_s_setprio(1); }
#define BAR1()    { __builtin_amdgcn_s_barrier();                               \
                    asm volatile("s_waitcnt lgkmcnt(0)" ::: "memory");          \
                    __builtin_amdgcn_sched_barrier(0);                          \
                    __builtin_amdgcn_s_setprio(1); }
#define BAR2()    { __builtin_amdgcn_s_setprio(0); __builtin_amdgcn_s_barrier(); }
#define BAR2V6()  { __builtin_amdgcn_s_setprio(0);                              \
                    asm volatile("s_waitcnt vmcnt(6)" ::: "memory");            \
                    __builtin_amdgcn_s_barrier(); }

template <bool OUTBF16>
__global__ __launch_bounds__(512, 1)
void gemm256_bt(const unsigned short* __restrict__ Ap, const unsigned short* __restrict__ Bp,
                void* __restrict__ Outp, int M, int N, int K)
{
  extern __shared__ __align__(16) char smem[];
  char* const As = smem;            // [2][256 rows][64 k] bf16, 64KB
  char* const Bs = smem + 65536;
  const int tid = threadIdx.x;
  const int wid = tid >> 6, lane = tid & 63;
  const int wm = wid >> 2, wn = wid & 3;
  const int lg = lane >> 4, lr = lane & 15;

  const int gx = gridDim.x;
  const int nwg = gx * (int)gridDim.y;
  int bid = (int)blockIdx.y * gx + (int)blockIdx.x;
  bid = (bid & 7) * (nwg >> 3) + (bid >> 3);   // bijective: nwg % 8 == 0
  const int m0 = (bid / gx) * 256, n0 = (bid % gx) * 256;

  const int srow8 = wid * 8 + (lane >> 3);
  const int scol  = (((lane & 7) ^ (lane >> 3)) << 3);
  const unsigned short* const Ag = Ap + (size_t)m0 * K;
  const unsigned short* const Bg = Bp + (size_t)n0 * K;

  const int cbs0 = (lg * 16) ^ ((lr & 7) << 4);
  const int cbs1 = (64 + lg * 16) ^ ((lr & 7) << 4);
  const int arow = (wm * 128 + lr) * 128;
  const int brow = (wn * 64 + lr) * 128;

  const f32x4 z4 = {0.f, 0.f, 0.f, 0.f};
  f32x4 acc[8][4];
#pragma unroll
  for (int i = 0; i < 8; ++i)
#pragma unroll
    for (int j = 0; j < 4; ++j) acc[i][j] = z4;

  const int NKT = K >> 6;
  bf16x8 af[4][2], bf01[2][2], bf23[2][2];

  // prologue: T0 A+B, T1 B, T1 A-h0 (14 loads); drain 8 oldest = T0 complete
  STG(As, Ag, 0, 0, 0); STG(As, Ag, 0, 1, 0);
  STG(Bs, Bg, 0, 0, 0); STG(Bs, Bg, 0, 1, 0);
  STG(Bs, Bg, 1, 0, 1); STG(Bs, Bg, 1, 1, 1);
  STG(As, Ag, 1, 0, 1);
  asm volatile("s_waitcnt vmcnt(6)" ::: "memory");
  __builtin_amdgcn_s_barrier();

  for (int it = 0; it < (NKT >> 1); ++it) {
    const int t1  = 2 * it + 1;
    const int t0n = (2 * it + 2 < NKT) ? 2 * it + 2 : NKT - 1;
    const int t1n = (t1 + 2 < NKT) ? t1 + 2 : NKT - 1;

    // ph0: reads T0 A-top+B-lo; stage A1h1 (buf1-A free since prev ph6)
    LDA(0, 0); LDB(0, 0, bf01); STG(As, Ag, 1, 1, t1);
    BAR1_12(); MM(0, 0, bf01); BAR2();
    // ph1
    LDB(0, 1, bf23);
    BAR1(); MM(0, 1, bf23); BAR2();
    // ph2: stage B0h0 (buf0-B free after ph1)
    LDA(0, 1); STG(Bs, Bg, 0, 0, t0n);
    BAR1(); MM(1, 0, bf01); BAR2();
    // ph3: stage B0h1 + A0h0 (buf0-A free after ph2); drain -> buf1 resident
    STG(Bs, Bg, 0, 1, t0n); STG(As, Ag, 0, 0, t0n);
    BAR1(); MM(1, 1, bf23); BAR2V6();
    // ph4: stage A0h1
    LDA(1, 0); LDB(1, 0, bf01); STG(As, Ag, 0, 1, t0n);
    BAR1_12(); MM(0, 0, bf01); BAR2();
    // ph5
    LDB(1, 1, bf23);
    BAR1(); MM(0, 1, bf23); BAR2();
    // ph6: stage B1h0 (buf1-B free after ph5)
    LDA(1, 1); STG(Bs, Bg, 1, 0, t1n);
    BAR1(); MM(1, 0, bf01); BAR2();
    // ph7: stage B1h1 + A1h0 (buf1-A free after ph6); drain -> buf0 resident
    STG(Bs, Bg, 1, 1, t1n); STG(As, Ag, 1, 0, t1n);
    BAR1(); MM(1, 1, bf23); BAR2V6();
  }
  asm volatile("s_waitcnt vmcnt(0)" ::: "memory");

#pragma unroll
  for (int i = 0; i < 8; ++i)
#pragma unroll
    for (int j = 0; j < 4; ++j)
#pragma unroll
      for (int r = 0; r < 4; ++r) {
        const int row = m0 + wm * 128 + i * 16 + lg * 4 + r;
        const int col = n0 + wn * 64 + j * 16 + lr;
        const float val = acc[i][j][r];
        if (OUTBF16) ((unsigned short*)Outp)[(size_t)row * N + col] = f2bf(val);
        else         ((float*)Outp)[(size_t)row * N + col] = val;
      }
}

// ---------------------------------------------------------------------------
// GEMM (m97 structure) + XCD swizzle — gemm3 (N=2048: 512 blocks).
// ---------------------------------------------------------------------------
template <bool OUTBF16>
__global__ __launch_bounds__(256, 2)
void gemm_bt16(const unsigned short* __restrict__ Ap, const unsigned short* __restrict__ Bp,
               void* __restrict__ Outp, int M, int N, int K)
{
  __shared__ __align__(16) char smA[128 * 128];
  __shared__ __align__(16) char smB[128 * 128];
  const int tid = threadIdx.x;
  const int wid = tid >> 6, lane = tid & 63;
  const int wr = wid >> 1, wc = wid & 1;
  const int lg = lane >> 4, lr = lane & 15;

  const int gx = gridDim.x;
  const int nwg = gx * gridDim.y;
  int bid = blockIdx.y * gx + blockIdx.x;
  bid = (bid & 7) * (nwg >> 3) + (bid >> 3);
  const int m0 = (bid / gx) * 128, n0 = (bid % gx) * 128;

  const int srow = wid * 8 + (lane >> 3);
  const int scol = (((lane & 7) ^ (lane >> 3)) << 3);
  const int lbase = wid * 1024;

  const f32x4 z4 = {0.f, 0.f, 0.f, 0.f};
  f32x4 acc[4][4];
#pragma unroll
  for (int i = 0; i < 4; ++i)
#pragma unroll
    for (int j = 0; j < 4; ++j) acc[i][j] = z4;

  for (int k0 = 0; k0 < K; k0 += 64) {
    __syncthreads();
#pragma unroll
    for (int c = 0; c < 4; ++c) {
      const int row = c * 32 + srow;
      gload16(Ap + (size_t)(m0 + row) * K + k0 + scol, smA + c * 4096 + lbase);
      gload16(Bp + (size_t)(n0 + row) * K + k0 + scol, smB + c * 4096 + lbase);
    }
    __syncthreads();
#pragma unroll
    for (int kk = 0; kk < 2; ++kk) {
      const int cb = (kk * 32 + lg * 8) * 2;
      bf16x8 a4[4], b4[4];
#pragma unroll
      for (int i = 0; i < 4; ++i) {
        const int row = wr * 64 + i * 16 + lr;
        a4[i] = *(const bf16x8*)(smA + row * 128 + (cb ^ ((row & 7) << 4)));
      }
#pragma unroll
      for (int j = 0; j < 4; ++j) {
        const int row = wc * 64 + j * 16 + lr;
        b4[j] = *(const bf16x8*)(smB + row * 128 + (cb ^ ((row & 7) << 4)));
      }
#pragma unroll
      for (int i = 0; i < 4; ++i)
#pragma unroll
        for (int j = 0; j < 4; ++j)
          acc[i][j] = __builtin_amdgcn_mfma_f32_16x16x32_bf16(a4[i], b4[j], acc[i][j], 0, 0, 0);
    }
  }
#pragma unroll
  for (int i = 0; i < 4; ++i)
#pragma unroll
    for (int j = 0; j < 4; ++j)
#pragma unroll
      for (int r = 0; r < 4; ++r) {
        const int row = m0 + wr * 64 + i * 16 + lg * 4 + r;
        const int col = n0 + wc * 64 + j * 16 + lr;
        const float val = acc[i][j][r];
        if (OUTBF16) ((unsigned short*)Outp)[(size_t)row * N + col] = f2bf(val);
        else         ((float*)Outp)[(size_t)row * N + col] = val;
      }
}

// ---------------------------------------------------------------------------
// V transpose: qkv V-part -> vT[(bh*128+d)*2048 + t]   (unchanged)
// ---------------------------------------------------------------------------
__global__ __launch_bounds__(256)
void vtrans(const unsigned short* __restrict__ qkv, unsigned short* __restrict__ vT)
{
  constexpr int T = 2048, ROWS = 6144;
  const int bh = blockIdx.y, b = bh >> 4, h = bh & 15;
  const int t0 = blockIdx.x * 64;
  const int tid = threadIdx.x;
  __shared__ __align__(16) char Sc[64 * 256];

#pragma unroll
  for (int c = 0; c < 4; ++c) {
    const int row = c * 16 + (tid >> 4);
    const int col = (tid & 15) * 8;
    u16x8 v = *(const u16x8*)(qkv + (size_t)(b * T + t0 + row) * ROWS + 4096 + h * 128 + col);
    *(u16x8*)(Sc + row * 256 + ((col * 2) ^ ((row & 7) << 4))) = v;
  }
  __syncthreads();
#pragma unroll
  for (int c = 0; c < 4; ++c) {
    const int d = c * 32 + (tid >> 3);
    const int t = (tid & 7) * 8;
    u16x8 v;
#pragma unroll
    for (int i = 0; i < 8; ++i)
      v[i] = *(const unsigned short*)(Sc + (t + i) * 256 + ((d * 2) ^ (((t + i) & 7) << 4)));
    *(u16x8*)(vT + ((size_t)bh * 128 + d) * 2048 + t0 + t) = v;
  }
}

// ---------------------------------------------------------------------------
// Flash attention v8: KVBLK=128; snake qt-permutation -> every CU gets
// exactly 34 K-tiles of work (was 28..40). log2 softmax; T13 defer-max.
// ---------------------------------------------------------------------------
__global__ __launch_bounds__(256, 2)
void attn_fwd(const unsigned short* __restrict__ qkv, const unsigned short* __restrict__ vT,
              unsigned short* __restrict__ outp)
{
  constexpr int T = 2048, ROWS = 6144;
  const int blk = blockIdx.x;
  const int g = blk >> 5;
  const int seg = g >> 3;
  // snake perm: balanced per-CU work (CU gets groups g, g+8, g+16, g+24)
  const int qt = (seg == 0) ? 31 - g : (seg == 1) ? g : (seg == 2) ? 39 - g : g - 24;
  const int bh = blk & 31;
  const int b = bh >> 4, h = bh & 15;
  const int q0 = qt * 64;
  const int tid = threadIdx.x;
  const int wid = tid >> 6, lane = tid & 63;
  const int lg = lane >> 4, lr = lane & 15;

  __shared__ __align__(16) char Ks[128 * 256];  // 32KB [128 k][128 d] swizzled
  __shared__ __align__(16) char Vt[128 * 256];  // 32KB [128 d][128 k] swizzled
  __shared__ __align__(16) char Ps[64 * 256];   // 16KB [64 q][128 k] swizzled

  const int srow = wid * 4 + (lane >> 4);
  const int scol = (((lane & 15) ^ (srow & 7)) << 3);

  const size_t qrow = (size_t)(b * T + q0 + wid * 16 + lr) * ROWS + h * 128;
  bf16x8 qf[4];
#pragma unroll
  for (int kd = 0; kd < 4; ++kd)
    qf[kd] = __builtin_bit_cast(bf16x8, *(const u16x8*)(qkv + qrow + kd * 32 + lg * 8));

  const f32x4 z4 = {0.f, 0.f, 0.f, 0.f};
  f32x4 oacc[8];
#pragma unroll
  for (int jj = 0; jj < 8; ++jj) oacc[jj] = z4;
  float mrow[4] = {-1e30f, -1e30f, -1e30f, -1e30f};
  float lsum[4] = {0.f, 0.f, 0.f, 0.f};
  const float scale2 = 0.12751745f;   // (1/sqrt(128)) * log2(e)

  const int nt = (qt >> 1) + 1;
  for (int kt = 0; kt < nt; ++kt) {
    __syncthreads();
#pragma unroll
    for (int c = 0; c < 8; ++c) {
      gload16(qkv + (size_t)(b * T + kt * 128 + c * 16 + srow) * ROWS + 2048 + h * 128 + scol,
              Ks + c * 4096 + wid * 1024);
      gload16(vT + ((size_t)bh * 128 + c * 16 + srow) * 2048 + kt * 128 + scol,
              Vt + c * 4096 + wid * 1024);
    }
    asm volatile("s_waitcnt vmcnt(0)" ::: "memory");
    __syncthreads();

    f32x4 sf[8];
#pragma unroll
    for (int j = 0; j < 8; ++j) sf[j] = z4;
#pragma unroll
    for (int kd = 0; kd < 4; ++kd) {
      const int cb = (kd * 32 + lg * 8) * 2;
#pragma unroll
      for (int j = 0; j < 8; ++j) {
        const int row = j * 16 + lr;
        bf16x8 kf = *(const bf16x8*)(Ks + row * 256 + (cb ^ ((row & 7) << 4)));
        sf[j] = __builtin_amdgcn_mfma_f32_16x16x32_bf16(qf[kd], kf, sf[j], 0, 0, 0);
      }
    }

    const bool diag = (kt == nt - 1);
#pragma unroll
    for (int j = 0; j < 8; ++j)
#pragma unroll
      for (int r = 0; r < 4; ++r) {
        float s = sf[j][r] * scale2;
        const int key = kt * 128 + j * 16 + lr;
        const int qi  = q0 + wid * 16 + lg * 4 + r;
        if (diag && key > qi) s = -1e30f;
        sf[j][r] = s;
      }
    float pm[4];
#pragma unroll
    for (int r = 0; r < 4; ++r) {
      float m0 = fmaxf(fmaxf(sf[0][r], sf[1][r]), fmaxf(sf[2][r], sf[3][r]));
      float m1 = fmaxf(fmaxf(sf[4][r], sf[5][r]), fmaxf(sf[6][r], sf[7][r]));
      pm[r] = red16max(fmaxf(m0, m1));
    }
    const float growth = fmaxf(fmaxf(pm[0] - mrow[0], pm[1] - mrow[1]),
                               fmaxf(pm[2] - mrow[2], pm[3] - mrow[3]));
    const bool resc = !__all(growth <= 11.5f);
    float alpha[4];
    if (resc) {
#pragma unroll
      for (int r = 0; r < 4; ++r) {
        const float mn = fmaxf(mrow[r], pm[r]);
        alpha[r] = exp2f(mrow[r] - mn);
        mrow[r] = mn;
      }
    }
    float rs[4] = {0.f, 0.f, 0.f, 0.f};
#pragma unroll
    for (int j = 0; j < 8; ++j)
#pragma unroll
      for (int r = 0; r < 4; ++r) {
        const float p = exp2f(sf[j][r] - mrow[r]);
        sf[j][r] = p;
        rs[r] += p;
      }
    if (resc) {
#pragma unroll
      for (int r = 0; r < 4; ++r) lsum[r] = lsum[r] * alpha[r] + red16sum(rs[r]);
    } else {
#pragma unroll
      for (int r = 0; r < 4; ++r) lsum[r] += red16sum(rs[r]);
    }

#pragma unroll
    for (int j = 0; j < 8; ++j)
#pragma unroll
      for (int r = 0; r < 4; ++r) {
        const int prow = wid * 16 + lg * 4 + r;
        const int pcol = j * 16 + lr;
        *(unsigned short*)(Ps + prow * 256 + ((pcol * 2) ^ ((prow & 7) << 4))) = f2bf(sf[j][r]);
      }
    if (resc) {
#pragma unroll
      for (int jj = 0; jj < 8; ++jj)
#pragma unroll
        for (int r = 0; r < 4; ++r) oacc[jj][r] *= alpha[r];
    }
    asm volatile("s_waitcnt lgkmcnt(0)" ::: "memory");
    __builtin_amdgcn_sched_barrier(0);

#pragma unroll
    for (int kk = 0; kk < 4; ++kk) {
      const int prow = wid * 16 + lr;
      const int pcb = (kk * 32 + lg * 8) * 2;
      bf16x8 pf = *(const bf16x8*)(Ps + prow * 256 + (pcb ^ ((prow & 7) << 4)));
#pragma unroll
      for (int jj = 0; jj < 8; ++jj) {
        const int vrow = jj * 16 + lr;
        bf16x8 vf = *(const bf16x8*)(Vt + vrow * 256 + (pcb ^ ((vrow & 7) << 4)));
        oacc[jj] = __builtin_amdgcn_mfma_f32_16x16x32_bf16(pf, vf, oacc[jj], 0, 0, 0);
      }
    }
  }

  // epilogue
#pragma unroll
  for (int jj = 0; jj < 8; ++jj)
#pragma unroll
    for (int r = 0; r < 4; ++r) {
      const int q = q0 + wid * 16 + lg * 4 + r;
      const int col = h * 128 + jj * 16 + lr;
      const float o = oacc[jj][r] / lsum[r];
      outp[(size_t)(b * T + q) * 2048 + col] = f2bf(o);
    }
}

// ---------------------------------------------------------------------------
extern "C" void kernel_launch(void* const* d_in, const int* in_sizes, int n_in,
                              void* d_out, int out_size, void* d_ws, size_t ws_size,
                              hipStream_t stream) {
  (void)in_sizes; (void)n_in; (void)out_size; (void)ws_size;
  const float* x     = (const float*)d_in[0];   // [2,2048,2048]
  const float* qkvw  = (const float*)d_in[1];   // [6144,2048]
  const float* projw = (const float*)d_in[2];   // [2048,2048]

  unsigned short* qkvb   = (unsigned short*)d_ws;               // [4096][6144]
  unsigned short* attnb  = qkvb   + (size_t)4096 * 6144;        // [4096][2048]
  unsigned short* xb     = attnb  + (size_t)4096 * 2048;        // [4096][2048]
  unsigned short* qkvwb  = xb     + (size_t)4096 * 2048;        // [6144][2048]
  unsigned short* projwb = qkvwb  + (size_t)6144 * 2048;        // [2048][2048]
  unsigned short* vT     = xb;                                  // overlay (xb dead after gemm1)
  float* out = (float*)d_out;                                   // [4096][2048] f32

  static bool attr_set = false;
  if (!attr_set) {
    hipFuncSetAttribute((const void*)gemm256_bt<true>,
                        hipFuncAttributeMaxDynamicSharedMemorySize, 131072);
    attr_set = true;
  }

  cvt3_f32_bf16<<<4096 + 6144 + 2048, 256, 0, stream>>>(
      x, xb, 4096, qkvw, qkvwb, 6144, projw, projwb);
  gemm256_bt<true><<<dim3(6144 / 256, 4096 / 256), 512, 131072, stream>>>(
      xb, qkvwb, qkvb, 4096, 6144, 2048);
  vtrans<<<dim3(32, 32), 256, 0, stream>>>(qkvb, vT);
  attn_fwd<<<1024, 256, 0, stream>>>(qkvb, vT, attnb);
  gemm_bt16<false><<<dim3(2048 / 128, 4096 / 128), 256, 0, stream>>>(
      attnb, projwb, out, 4096, 2048, 2048);
}